// Round 12
// baseline (286.044 us; speedup 1.0000x reference)
//
#include <hip/hip_runtime.h>
#include <hip/hip_bf16.h>

// ---------- types ----------
typedef __attribute__((ext_vector_type(8))) short    short8;
typedef __attribute__((ext_vector_type(4))) float    f32x4;
typedef __attribute__((ext_vector_type(4))) _Float16 f16x4;
typedef __attribute__((ext_vector_type(2))) unsigned u32x2;
typedef __attribute__((ext_vector_type(4))) unsigned u32x4;

#define NCLS 10
#define TILE 128           // rows per tile (4 k-slices of 32)
#define NW   10            // waves: 0-7 stage+convert+compute, 8-9 masks+compute
#define TPB  (NW * 64)     // 640 threads
#define NQ   10            // upper-triangular 16x16 quads of 64x64 Gram
#define PPB  (NCLS * NQ * 256)   // halves per block of partials
#define CH   16            // reduction chunks

#define MF(a, b, c) __builtin_amdgcn_mfma_f32_16x16x32_bf16((a), (b), (c), 0, 0, 0)

static __device__ __forceinline__ unsigned pkbf2(float a, float b) {
    __hip_bfloat162 p = __float22bfloat162_rn(make_float2(a, b));
    unsigned u; __builtin_memcpy(&u, &p, 4);
    return u;
}
static __device__ __forceinline__ unsigned pkh2(float a, float b) {
    unsigned short ha = __builtin_bit_cast(unsigned short, (_Float16)a);
    unsigned short hb = __builtin_bit_cast(unsigned short, (_Float16)b);
    return (unsigned)ha | ((unsigned)hb << 16);
}
static __device__ __forceinline__ unsigned umin2(unsigned a, unsigned b) {
    return a < b ? a : b;
}

// ---------- compute one tile: one full class per wave, both operands masked ----------
// bf16 tile layout: byte(d, row) = d*256 + ((rg*16) ^ ((d&7)<<4)) + (row&7)*2,
// rg = row>>3.  All reads verified 8-lane/4-bank-group optimal (0 conflicts).
static __device__ __forceinline__ void compute_tile(
        const char* hsb, const char* mkb, int cls, int hi, int col,
        f32x4 (&acc)[NQ]) {
    const int r0 = col * 256 + ((hi * 16) ^ ((col & 7) << 4));
    const int r1 = r0 ^ 64;
    const char* mb = mkb + cls * 256 + hi * 16;
#pragma unroll
    for (int ks = 0; ks < 4; ++ks) {
        const int ro = ((ks & 1) ? r1 : r0) + (ks >> 1) * 128;
        const short8 m = *(const short8*)(mb + ks * 64);
        short8 am[4];
#pragma unroll
        for (int nb = 0; nb < 4; ++nb)
            am[nb] = *(const short8*)(hsb + ro + nb * 4096) & m;
        acc[0] = MF(am[0], am[0], acc[0]);
        acc[1] = MF(am[0], am[1], acc[1]);
        acc[2] = MF(am[0], am[2], acc[2]);
        acc[3] = MF(am[0], am[3], acc[3]);
        acc[4] = MF(am[1], am[1], acc[4]);
        acc[5] = MF(am[1], am[2], acc[5]);
        acc[6] = MF(am[1], am[3], acc[6]);
        acc[7] = MF(am[2], am[2], acc[7]);
        acc[8] = MF(am[2], am[3], acc[8]);
        acc[9] = MF(am[3], am[3], acc[9]);
    }
}

// ---------- kernel 1: masked Grams; reg-staged, ONE barrier per tile ----------
// partials: [G][NCLS][NQ][256] f16; cntp: [G][16] int. Both fully overwritten.
__global__ __launch_bounds__(TPB, 5) void HL_gram(
        const float* __restrict__ h, const int* __restrict__ yhat,
        _Float16* __restrict__ partials, int* __restrict__ cntp,
        int N, int ntiles, int G) {
    __shared__ __align__(16) unsigned short hs[2][64 * TILE];    // 32 KB bf16 swz
    __shared__ __align__(16) unsigned short mk[2][NCLS * TILE];  // 5 KB masks
    __shared__ int cntlds[16];

    const int tid  = threadIdx.x;
    const int wid  = tid >> 6;      // 0..9; wave owns class wid
    const int lane = tid & 63;
    const int hi   = lane >> 4;
    const int col  = lane & 15;
    const int cls  = wid;

    if (tid < 16) cntlds[tid] = 0;

    f32x4 acc[NQ];
#pragma unroll
    for (int q = 0; q < NQ; ++q) acc[q] = (f32x4){0.f, 0.f, 0.f, 0.f};
    int c0=0,c1=0,c2=0,c3=0,c4=0,c5=0,c6=0,c7=0,c8=0,c9=0;   // waves 8/9

    const int bid = blockIdx.x;
    const int K   = (ntiles - bid + G - 1) / G;

    // clamps (per-thread, constant)
    const unsigned maxh = (unsigned)(N - 8) * 256u + (unsigned)lane * 4u;
    const unsigned maxy = (unsigned)(N - 1) * 4u;
    const int yhalf = (wid - 8) * 64;        // 0 for wave8, 64 for wave9

    float xA[16], xB[16];
    int   yA = -1, yB = -1;

    // ---- STAGE tile t into register set (waves 0-7: 16 rows; 8/9: y) ----
#define STAGE(X, t)                                                            \
    {                                                                          \
        if (wid < 8) {                                                         \
            const unsigned ub = (unsigned)(t) * (TILE * 256u)                  \
                              + (unsigned)wid * 2048u + (unsigned)lane * 4u;   \
            const unsigned o0 = umin2(ub, maxh);                               \
            const unsigned o1 = umin2(ub + 16384u, maxh);                      \
            _Pragma("unroll")                                                  \
            for (int j = 0; j < 8; ++j)                                        \
                x##X[j] = *(const float*)((const char*)h + o0 + j * 256);      \
            _Pragma("unroll")                                                  \
            for (int j = 0; j < 8; ++j)                                        \
                x##X[8 + j] = *(const float*)((const char*)h + o1 + j * 256);  \
        } else {                                                               \
            const unsigned oy = umin2((unsigned)(t) * (TILE * 4u)              \
                                      + (unsigned)(lane + yhalf) * 4u, maxy);  \
            y##X = *(const int*)((const char*)yhat + oy);                      \
        }                                                                      \
    }

    // ---- CONVERT set -> LDS slot; masks + counts on waves 8/9 ----
#define CONVERT(X, slot, t)                                                    \
    {                                                                          \
        if (wid < 8) {                                                         \
            u32x4 vlo, vhi;                                                    \
            vlo[0] = pkbf2(x##X[0],  x##X[1]);                                 \
            vlo[1] = pkbf2(x##X[2],  x##X[3]);                                 \
            vlo[2] = pkbf2(x##X[4],  x##X[5]);                                 \
            vlo[3] = pkbf2(x##X[6],  x##X[7]);                                 \
            vhi[0] = pkbf2(x##X[8],  x##X[9]);                                 \
            vhi[1] = pkbf2(x##X[10], x##X[11]);                                \
            vhi[2] = pkbf2(x##X[12], x##X[13]);                                \
            vhi[3] = pkbf2(x##X[14], x##X[15]);                                \
            char* hb = (char*)&hs[slot][0] + lane * 256                        \
                       + ((wid * 16) ^ ((lane & 7) << 4));                     \
            *(u32x4*)hb         = vlo;                                         \
            *(u32x4*)(hb + 128) = vhi;                                         \
        } else {                                                               \
            int y = y##X;                                                      \
            if ((t) * TILE + lane + yhalf >= N) y = -1;                        \
            unsigned short* mw = &mk[slot][0];                                 \
            const int r = lane + yhalf;                                        \
            _Pragma("unroll")                                                  \
            for (int c = 0; c < NCLS; ++c)                                     \
                mw[c * TILE + r] = (y == c) ? (unsigned short)0xFFFFu          \
                                            : (unsigned short)0u;              \
            c0 += (int)__popcll(__ballot(y == 0));                             \
            c1 += (int)__popcll(__ballot(y == 1));                             \
            c2 += (int)__popcll(__ballot(y == 2));                             \
            c3 += (int)__popcll(__ballot(y == 3));                             \
            c4 += (int)__popcll(__ballot(y == 4));                             \
            c5 += (int)__popcll(__ballot(y == 5));                             \
            c6 += (int)__popcll(__ballot(y == 6));                             \
            c7 += (int)__popcll(__ballot(y == 7));                             \
            c8 += (int)__popcll(__ballot(y == 8));                             \
            c9 += (int)__popcll(__ballot(y == 9));                             \
        }                                                                      \
    }

#define BAR()                                                                  \
    asm volatile("s_waitcnt lgkmcnt(0)" ::: "memory");                         \
    __builtin_amdgcn_s_barrier();                                              \
    __builtin_amdgcn_sched_barrier(0);

    STAGE(A, bid);

    for (int k = 0; k < K; k += 2) {
        // ---- phase k: stage(k+1), convert A -> slot0, barrier, compute ----
        if (k + 1 < K) STAGE(B, bid + (k + 1) * G);
        __builtin_amdgcn_sched_barrier(0);
        CONVERT(A, 0, bid + k * G);
        BAR();
        compute_tile((const char*)&hs[0][0], (const char*)&mk[0][0],
                     cls, hi, col, acc);
        if (k + 1 >= K) break;

        // ---- phase k+1: stage(k+2), convert B -> slot1, barrier, compute ----
        if (k + 2 < K) STAGE(A, bid + (k + 2) * G);
        __builtin_amdgcn_sched_barrier(0);
        CONVERT(B, 1, bid + (k + 1) * G);
        BAR();
        compute_tile((const char*)&hs[1][0], (const char*)&mk[1][0],
                     cls, hi, col, acc);
        // Safety of slot reuse: every wave's compute(slot0) of phase k precedes
        // its barrier of phase k+1, which precedes any wave's CONVERT into
        // slot0 at phase k+2.  One barrier per tile suffices.
    }

    // ---- epilogue: merge counts, stream partials ----
    if (wid >= 8 && lane == 0) {
        atomicAdd(&cntlds[0], c0); atomicAdd(&cntlds[1], c1);
        atomicAdd(&cntlds[2], c2); atomicAdd(&cntlds[3], c3);
        atomicAdd(&cntlds[4], c4); atomicAdd(&cntlds[5], c5);
        atomicAdd(&cntlds[6], c6); atomicAdd(&cntlds[7], c7);
        atomicAdd(&cntlds[8], c8); atomicAdd(&cntlds[9], c9);
    }
    __syncthreads();

    _Float16* po = partials + (size_t)bid * PPB + (size_t)cls * (NQ * 256);
#pragma unroll
    for (int q = 0; q < NQ; ++q) {
        u32x2 pk;
        pk[0] = pkh2(acc[q][0], acc[q][1]);
        pk[1] = pkh2(acc[q][2], acc[q][3]);
        *(u32x2*)(po + q * 256 + (lane << 2)) = pk;
    }
    if (tid < NCLS) cntp[bid * 16 + tid] = cntlds[tid];
}

// ---------- kernel 2: chunked block-reduction of f16 partials (atomic-free) ----------
__global__ void HL_reduce(const _Float16* __restrict__ partials, float* __restrict__ rpart,
                          float* __restrict__ out, int G, int CS) {
    const int idx = blockIdx.x * blockDim.x + threadIdx.x;
    if (blockIdx.x == 0 && threadIdx.x == 0) out[0] = 0.f;
    if (idx >= CH * NCLS * NQ * 64) return;
    const int ch = idx / (NCLS * NQ * 64);
    const int r  = idx % (NCLS * NQ * 64);
    const int cq = r >> 6;
    const int l  = r & 63;

    int b0 = ch * CS;
    int b1 = b0 + CS; if (b1 > G) b1 = G;

    f32x4 s = (f32x4){0.f, 0.f, 0.f, 0.f};
    const _Float16* p = partials + (size_t)cq * 256 + (l << 2);
    for (int b = b0; b < b1; ++b) {
        f16x4 v = *(const f16x4*)(p + (size_t)b * PPB);
        s[0] += (float)v[0]; s[1] += (float)v[1];
        s[2] += (float)v[2]; s[3] += (float)v[3];
    }
    *reinterpret_cast<f32x4*>(rpart + ((size_t)ch * (NCLS * NQ) + cq) * 256 + (l << 2)) = s;
}

// ---------- kernel 3: counts + M = 0.5*G/cnt + I; loss += 0.5*logdet ----------
__global__ __launch_bounds__(64, 1) void HL_chol(
        const float* __restrict__ rpart, const int* __restrict__ cntp,
        float* __restrict__ out, int G) {
    __shared__ float M[64][68];
    __shared__ float lcol[64];
    const int cls = blockIdx.x;
    const int i   = threadIdx.x;   // lane 0..63

    int c = 0;
    for (int b = i; b < G; b += 64) c += cntp[b * 16 + cls];
#pragma unroll
    for (int off = 32; off > 0; off >>= 1) c += __shfl_xor(c, off);
    const float inv = 0.5f / (float)c;

    const int QMB[NQ] = {0,0,0,0,1,1,1,2,2,3};
    const int QNB[NQ] = {0,1,2,3,1,2,3,2,3,3};
    const float* rp = rpart + (size_t)cls * (NQ * 256);
#pragma unroll
    for (int q = 0; q < NQ; ++q) {
        f32x4 s = (f32x4){0.f, 0.f, 0.f, 0.f};
#pragma unroll
        for (int ch = 0; ch < CH; ++ch)
            s += *reinterpret_cast<const f32x4*>(rp + (size_t)ch * (NCLS * NQ * 256) + q * 256 + (i << 2));
        const int row0 = QMB[q] * 16 + ((i >> 4) << 2);
        const int colo = QNB[q] * 16 + (i & 15);
#pragma unroll
        for (int rr = 0; rr < 4; ++rr) {
            M[row0 + rr][colo] = s[rr];
            M[colo][row0 + rr] = s[rr];
        }
    }
    __syncthreads();

    float row[64];
#pragma unroll
    for (int c2 = 0; c2 < 64; ++c2)
        row[c2] = M[i][c2] * inv + (c2 == i ? 1.0f : 0.0f);

#pragma unroll
    for (int j = 0; j < 64; ++j) {
        const float piv = __shfl(row[j], j);
        const float li  = row[j] * rsqrtf(piv);
        lcol[i] = li;
        __syncthreads();
#pragma unroll
        for (int c2 = j + 1; c2 < 64; ++c2)
            row[c2] -= li * lcol[c2];
        __syncthreads();
    }

    float slog = 0.f;
#pragma unroll
    for (int j = 0; j < 64; ++j)
        if (i == j) slog = __logf(row[j]);
    slog += __shfl_down(slog, 32); slog += __shfl_down(slog, 16);
    slog += __shfl_down(slog, 8);  slog += __shfl_down(slog, 4);
    slog += __shfl_down(slog, 2);  slog += __shfl_down(slog, 1);
    if (i == 0) atomicAdd(out, 0.5f * slog);
}

// ---------- launcher ----------
extern "C" void kernel_launch(void* const* d_in, const int* in_sizes, int n_in,
                              void* d_out, int out_size, void* d_ws, size_t ws_size,
                              hipStream_t stream) {
    const float* h    = (const float*)d_in[0];
    const int*   yhat = (const int*)d_in[1];
    const int    N    = in_sizes[1];
    float* out = (float*)d_out;

    // ws layout: [rpart CH*100*256 f32][cntp G*16 int][partials G*PPB f16]
    const size_t rpart_sz = (size_t)CH * NCLS * NQ * 256 * sizeof(float);
    const size_t cntp_off = rpart_sz;

    const int ntiles = (N + TILE - 1) / TILE;
    int G = 512;    // 2 blocks per CU
    {
        const size_t perG = 64 + (size_t)PPB * sizeof(_Float16);
        if (ws_size > rpart_sz) {
            size_t maxG = (ws_size - rpart_sz) / perG;
            if ((size_t)G > maxG) G = (int)maxG;
        } else G = 1;
        if (G < 1) G = 1;
    }
    if (G > ntiles) G = ntiles;

    const size_t partials_off = cntp_off + (size_t)G * 16 * sizeof(int);
    float*    rpart    = (float*)d_ws;
    int*      cntp     = (int*)((char*)d_ws + cntp_off);
    _Float16* partials = (_Float16*)((char*)d_ws + partials_off);

    HL_gram<<<G, TPB, 0, stream>>>(h, yhat, partials, cntp, N, ntiles, G);

    int CS = (G + CH - 1) / CH;
    const int rthreads = CH * NCLS * NQ * 64;
    HL_reduce<<<(rthreads + 255) / 256, 256, 0, stream>>>(partials, rpart, out, G, CS);

    HL_chol<<<NCLS, 64, 0, stream>>>(rpart, cntp, out, G);
}

// Round 13
// 140.056 us; speedup vs baseline: 2.0424x; 2.0424x over previous
//
#include <hip/hip_runtime.h>
#include <hip/hip_bf16.h>

// ---------- types ----------
typedef __attribute__((ext_vector_type(8))) short    short8;
typedef __attribute__((ext_vector_type(4))) float    f32x4;
typedef __attribute__((ext_vector_type(4))) _Float16 f16x4;
typedef __attribute__((ext_vector_type(2))) unsigned u32x2;
typedef __attribute__((ext_vector_type(4))) int      i32x4;

#define NCLS 10
#define TILE 64            // rows per tile (2 k-slices of 32)
#define TPB  512           // 8 waves; 2 blocks/CU
#define NQ   10            // upper-triangular 16x16 quads of 64x64 Gram
#define PPB  (NCLS * NQ * 256)   // halves per block of partials
#define CH   16            // reduction chunks

#define AS1 __attribute__((address_space(1)))
#define AS3 __attribute__((address_space(3)))

#define MF(a, b, c) __builtin_amdgcn_mfma_f32_16x16x32_bf16((a), (b), (c), 0, 0, 0)

static __device__ __forceinline__ unsigned pkbf2(float a, float b) {
    __hip_bfloat162 p = __float22bfloat162_rn(make_float2(a, b));
    unsigned u; __builtin_memcpy(&u, &p, 4);
    return u;
}
static __device__ __forceinline__ unsigned pkh2(float a, float b) {
    unsigned short ha = __builtin_bit_cast(unsigned short, (_Float16)a);
    unsigned short hb = __builtin_bit_cast(unsigned short, (_Float16)b);
    return (unsigned)ha | ((unsigned)hb << 16);
}
static __device__ __forceinline__ unsigned umin2(unsigned a, unsigned b) {
    return a < b ? a : b;
}

// ---------- compute one tile; masks built IN-REGISTER from the y tile ----------
// hs layout (R11-proven, 0 bank conflicts): byte(d, rowgrp w) =
//   d*128 + ((w*16) ^ ((d&7)<<4)) + (row&7)*2
static __device__ __forceinline__ void compute_tile(
        const char* hsb, const char* yb, int vr,
        int cls, int xcls, int wq, int hi, int col,
        f32x4 (&acc)[NQ], f32x4 (&accx)[3], int& cnt, int& cntx) {
    const int s56 = (col & 3) << 4;
    const int s6  = (col & 4) << 4;
    const char* rb0 = hsb + col * 128 + ((hi * 16) ^ s56) + s6;         // ks=0
    const char* rb1 = hsb + col * 128 + ((hi * 16) ^ s56) + (64 ^ s6);  // ks=1

#pragma unroll
    for (int ks = 0; ks < 2; ++ks) {
        const char* rb   = ks ? rb1 : rb0;
        const int   krow = ks * 32 + hi * 8;

        // ---- y values for this lane's 8 k-rows (broadcast LDS reads) ----
        i32x4 ya = *(const i32x4*)(yb + ks * 128 + hi * 32);
        i32x4 yc = *(const i32x4*)(yb + ks * 128 + hi * 32 + 16);
        ya[0] = (krow + 0 < vr) ? ya[0] : -1;
        ya[1] = (krow + 1 < vr) ? ya[1] : -1;
        ya[2] = (krow + 2 < vr) ? ya[2] : -1;
        ya[3] = (krow + 3 < vr) ? ya[3] : -1;
        yc[0] = (krow + 4 < vr) ? yc[0] : -1;
        yc[1] = (krow + 5 < vr) ? yc[1] : -1;
        yc[2] = (krow + 6 < vr) ? yc[2] : -1;
        yc[3] = (krow + 7 < vr) ? yc[3] : -1;

        short8 m, mx;
        m[0] = (ya[0] == cls) ? (short)-1 : (short)0;
        m[1] = (ya[1] == cls) ? (short)-1 : (short)0;
        m[2] = (ya[2] == cls) ? (short)-1 : (short)0;
        m[3] = (ya[3] == cls) ? (short)-1 : (short)0;
        m[4] = (yc[0] == cls) ? (short)-1 : (short)0;
        m[5] = (yc[1] == cls) ? (short)-1 : (short)0;
        m[6] = (yc[2] == cls) ? (short)-1 : (short)0;
        m[7] = (yc[3] == cls) ? (short)-1 : (short)0;
        mx[0] = (ya[0] == xcls) ? (short)-1 : (short)0;
        mx[1] = (ya[1] == xcls) ? (short)-1 : (short)0;
        mx[2] = (ya[2] == xcls) ? (short)-1 : (short)0;
        mx[3] = (ya[3] == xcls) ? (short)-1 : (short)0;
        mx[4] = (yc[0] == xcls) ? (short)-1 : (short)0;
        mx[5] = (yc[1] == xcls) ? (short)-1 : (short)0;
        mx[6] = (yc[2] == xcls) ? (short)-1 : (short)0;
        mx[7] = (yc[3] == xcls) ? (short)-1 : (short)0;
        cnt  += (ya[0] == cls)  + (ya[1] == cls)  + (ya[2] == cls)  + (ya[3] == cls)
              + (yc[0] == cls)  + (yc[1] == cls)  + (yc[2] == cls)  + (yc[3] == cls);
        cntx += (ya[0] == xcls) + (ya[1] == xcls) + (ya[2] == xcls) + (ya[3] == xcls)
              + (yc[0] == xcls) + (yc[1] == xcls) + (yc[2] == xcls) + (yc[3] == xcls);

        short8 raw[4], am[4];
#pragma unroll
        for (int nb = 0; nb < 4; ++nb) {
            raw[nb] = *(const short8*)(rb + nb * 2048);
            am[nb]  = raw[nb] & m;
        }
        __builtin_amdgcn_s_setprio(1);
        acc[0] = MF(am[0], am[0], acc[0]);
        acc[1] = MF(am[0], am[1], acc[1]);
        acc[2] = MF(am[0], am[2], acc[2]);
        acc[3] = MF(am[0], am[3], acc[3]);
        acc[4] = MF(am[1], am[1], acc[4]);
        acc[5] = MF(am[1], am[2], acc[5]);
        acc[6] = MF(am[1], am[3], acc[6]);
        acc[7] = MF(am[2], am[2], acc[7]);
        acc[8] = MF(am[2], am[3], acc[8]);
        acc[9] = MF(am[3], am[3], acc[9]);
        switch (wq) {
        case 0: { short8 x0 = raw[0] & mx, x1 = raw[1] & mx;
                  accx[0] = MF(x0, x0, accx[0]);
                  accx[1] = MF(x0, x1, accx[1]);
                  accx[2] = MF(x1, x1, accx[2]); } break;
        case 1: { short8 x0 = raw[0] & mx, x2 = raw[2] & mx, x3 = raw[3] & mx;
                  accx[0] = MF(x0, x2, accx[0]);
                  accx[1] = MF(x0, x3, accx[1]); } break;
        case 2: { short8 x1 = raw[1] & mx, x2 = raw[2] & mx, x3 = raw[3] & mx;
                  accx[0] = MF(x1, x2, accx[0]);
                  accx[1] = MF(x1, x3, accx[1]);
                  accx[2] = MF(x2, x2, accx[2]); } break;
        default:{ short8 x2 = raw[2] & mx, x3 = raw[3] & mx;
                  accx[0] = MF(x2, x3, accx[0]);
                  accx[1] = MF(x3, x3, accx[1]); } break;
        }
        __builtin_amdgcn_s_setprio(0);
    }
}

// ---------- kernel 1: masked Grams; 1 barrier/tile; in-register masks ----------
// partials: [G][NCLS][NQ][256] f16; cntp: [G][16] int. Both fully overwritten.
__global__ __launch_bounds__(TPB, 4) void HL_gram(
        const float* __restrict__ h, const int* __restrict__ yhat,
        _Float16* __restrict__ partials, int* __restrict__ cntp,
        int N, int ntiles, int G) {
    __shared__ __align__(16) float          fs[2][TILE * 64];    // 32 KB fp32
    __shared__ __align__(16) unsigned short hs[2][64 * TILE];    // 16 KB bf16 swz
    __shared__ __align__(16) int            ylds[4][TILE];       // 1 KB, 4-slot ring

    const int tid  = threadIdx.x;
    const int wid  = tid >> 6;      // 0..7; wave owns class wid (+ xcls slice)
    const int lane = tid & 63;
    const int hi   = lane >> 4;
    const int col  = lane & 15;

    const int cls  = wid;
    const int xcls = 8 + (wid >> 2);
    const int wq   = wid & 3;

    f32x4 acc[NQ], accx[3];
#pragma unroll
    for (int q = 0; q < NQ; ++q) acc[q] = (f32x4){0.f, 0.f, 0.f, 0.f};
#pragma unroll
    for (int q = 0; q < 3; ++q)  accx[q] = (f32x4){0.f, 0.f, 0.f, 0.f};
    int cnt = 0, cntx = 0;

    const int bid = blockIdx.x;
    const int K   = (ntiles - bid + G - 1) / G;

    // ---- 32-bit additive DMA source offsets (bytes) ----
    const unsigned step  = (unsigned)G * (TILE * 256u);
    const unsigned maxh  = (unsigned)(N - 1) * 256u + (unsigned)(tid & 15) * 16u;
    unsigned offh = ((unsigned)bid * TILE + (unsigned)(tid >> 4)) * 256u
                  + (unsigned)(tid & 15) * 16u;
    const unsigned ystep = (unsigned)G * (TILE * 4u);
    const unsigned maxy  = (unsigned)(N - 4) * 4u;
    unsigned offy = (unsigned)bid * (TILE * 4u) + (unsigned)lane * 16u;

    char* fdst0 = (char*)&fs[0][0] + wid * 1024;   // wave-uniform LDS dests
    char* fdst1 = (char*)&fs[1][0] + wid * 1024;

    // ---- prologue: DMA tile 0 -> fs[0], ylds[0] ----
    {
        const unsigned o0 = umin2(offh, maxh);
        const unsigned o1 = umin2(offh + 8192u, maxh);
        __builtin_amdgcn_global_load_lds((const AS1 float*)((const char*)h + o0),
                                         (AS3 float*)fdst0, 16, 0, 0);
        __builtin_amdgcn_global_load_lds((const AS1 float*)((const char*)h + o1),
                                         (AS3 float*)(fdst0 + 8192), 16, 0, 0);
        if (wid == 7 && lane < 16) {
            const unsigned oy = umin2(offy, maxy);
            __builtin_amdgcn_global_load_lds((const AS1 int*)((const char*)yhat + oy),
                                             (AS3 int*)&ylds[0][0], 16, 0, 0);
        }
        offh += step; offy += ystep;
    }

    for (int k = 0; k < K; ++k) {
        const int slot = k & 1;

        // ---- entry: DMA(k) drained; phase-(k-1) LDS writes visible ----
        asm volatile("s_waitcnt vmcnt(0)" ::: "memory");
        asm volatile("s_waitcnt lgkmcnt(0)" ::: "memory");
        __builtin_amdgcn_s_barrier();
        __builtin_amdgcn_sched_barrier(0);

        // ---- issue DMA(k+1): fs[slot^1], ylds[(k+1)&3] ----
        if (k + 1 < K) {
            char* fd = slot ? fdst0 : fdst1;
            const unsigned o0 = umin2(offh, maxh);
            const unsigned o1 = umin2(offh + 8192u, maxh);
            __builtin_amdgcn_global_load_lds((const AS1 float*)((const char*)h + o0),
                                             (AS3 float*)fd, 16, 0, 0);
            __builtin_amdgcn_global_load_lds((const AS1 float*)((const char*)h + o1),
                                             (AS3 float*)(fd + 8192), 16, 0, 0);
            if (wid == 7 && lane < 16) {
                const unsigned oy = umin2(offy, maxy);
                __builtin_amdgcn_global_load_lds((const AS1 int*)((const char*)yhat + oy),
                                                 (AS3 int*)&ylds[(k + 1) & 3][0], 16, 0, 0);
            }
            offh += step; offy += ystep;
        }

        // ---- convert tile k: wave w owns rows w*8..+7, lane = d ----
        {
            const float* fp = &fs[slot][0] + wid * 512 + lane;
            const float x0 = fp[0],   x1 = fp[64],  x2 = fp[128], x3 = fp[192];
            const float x4 = fp[256], x5 = fp[320], x6 = fp[384], x7 = fp[448];
            u32x2 lo, hi2;
            lo[0]  = pkbf2(x0, x1); lo[1]  = pkbf2(x2, x3);
            hi2[0] = pkbf2(x4, x5); hi2[1] = pkbf2(x6, x7);
            char* hb = (char*)&hs[slot][0] + lane * 128 + ((wid * 16) ^ ((lane & 7) << 4));
            *(u32x2*)hb       = lo;
            *(u32x2*)(hb + 8) = hi2;
        }

        // ---- compute tile k-1 (hs[slot^1], ylds[(k-1)&3]) ----
        if (k > 0) {
            const int vr = N - (bid + (k - 1) * G) * TILE;
            compute_tile((const char*)&hs[slot ^ 1][0], (const char*)&ylds[(k - 1) & 3][0],
                         vr, cls, xcls, wq, hi, col, acc, accx, cnt, cntx);
        }
    }

    // ---- epilogue: compute the last converted tile ----
    asm volatile("s_waitcnt lgkmcnt(0)" ::: "memory");
    __builtin_amdgcn_s_barrier();
    __builtin_amdgcn_sched_barrier(0);
    {
        const int vr = N - (bid + (K - 1) * G) * TILE;
        compute_tile((const char*)&hs[(K - 1) & 1][0], (const char*)&ylds[(K - 1) & 3][0],
                     vr, cls, xcls, wq, hi, col, acc, accx, cnt, cntx);
    }

    // ---- counts: reduce across hi groups (cols hold identical values) ----
    cnt  += __shfl_xor(cnt, 16);  cnt  += __shfl_xor(cnt, 32);
    cntx += __shfl_xor(cntx, 16); cntx += __shfl_xor(cntx, 32);

    // ---- stream partials (f16) + per-block counts ----
    _Float16* pb = partials + (size_t)bid * PPB;
    {
        _Float16* po = pb + (size_t)cls * (NQ * 256);
#pragma unroll
        for (int q = 0; q < NQ; ++q) {
            u32x2 pk;
            pk[0] = pkh2(acc[q][0], acc[q][1]);
            pk[1] = pkh2(acc[q][2], acc[q][3]);
            *(u32x2*)(po + q * 256 + (lane << 2)) = pk;
        }
    }
    {
        _Float16* px = pb + (size_t)xcls * (NQ * 256) + (lane << 2);
        u32x2 pk0, pk1, pk2;
        pk0[0] = pkh2(accx[0][0], accx[0][1]); pk0[1] = pkh2(accx[0][2], accx[0][3]);
        pk1[0] = pkh2(accx[1][0], accx[1][1]); pk1[1] = pkh2(accx[1][2], accx[1][3]);
        pk2[0] = pkh2(accx[2][0], accx[2][1]); pk2[1] = pkh2(accx[2][2], accx[2][3]);
        switch (wq) {
        case 0: *(u32x2*)(px + 0 * 256) = pk0;
                *(u32x2*)(px + 1 * 256) = pk1;
                *(u32x2*)(px + 4 * 256) = pk2; break;
        case 1: *(u32x2*)(px + 2 * 256) = pk0;
                *(u32x2*)(px + 3 * 256) = pk1; break;
        case 2: *(u32x2*)(px + 5 * 256) = pk0;
                *(u32x2*)(px + 6 * 256) = pk1;
                *(u32x2*)(px + 7 * 256) = pk2; break;
        default:*(u32x2*)(px + 8 * 256) = pk0;
                *(u32x2*)(px + 9 * 256) = pk1; break;
        }
    }
    if (lane == 0) {
        cntp[bid * 16 + cls] = cnt;
        if (wq == 0) cntp[bid * 16 + xcls] = cntx;
    }
}

// ---------- kernel 2: chunked block-reduction of f16 partials (atomic-free) ----------
__global__ void HL_reduce(const _Float16* __restrict__ partials, float* __restrict__ rpart,
                          float* __restrict__ out, int G, int CS) {
    const int idx = blockIdx.x * blockDim.x + threadIdx.x;
    if (blockIdx.x == 0 && threadIdx.x == 0) out[0] = 0.f;
    if (idx >= CH * NCLS * NQ * 64) return;
    const int ch = idx / (NCLS * NQ * 64);
    const int r  = idx % (NCLS * NQ * 64);
    const int cq = r >> 6;
    const int l  = r & 63;

    int b0 = ch * CS;
    int b1 = b0 + CS; if (b1 > G) b1 = G;

    f32x4 s = (f32x4){0.f, 0.f, 0.f, 0.f};
    const _Float16* p = partials + (size_t)cq * 256 + (l << 2);
    for (int b = b0; b < b1; ++b) {
        f16x4 v = *(const f16x4*)(p + (size_t)b * PPB);
        s[0] += (float)v[0]; s[1] += (float)v[1];
        s[2] += (float)v[2]; s[3] += (float)v[3];
    }
    *reinterpret_cast<f32x4*>(rpart + ((size_t)ch * (NCLS * NQ) + cq) * 256 + (l << 2)) = s;
}

// ---------- kernel 3: counts + M = 0.5*G/cnt + I; loss += 0.5*logdet ----------
__global__ __launch_bounds__(64, 1) void HL_chol(
        const float* __restrict__ rpart, const int* __restrict__ cntp,
        float* __restrict__ out, int G) {
    __shared__ float M[64][68];
    __shared__ float lcol[64];
    const int cls = blockIdx.x;
    const int i   = threadIdx.x;   // lane 0..63

    int c = 0;
    for (int b = i; b < G; b += 64) c += cntp[b * 16 + cls];
#pragma unroll
    for (int off = 32; off > 0; off >>= 1) c += __shfl_xor(c, off);
    const float inv = 0.5f / (float)c;

    const int QMB[NQ] = {0,0,0,0,1,1,1,2,2,3};
    const int QNB[NQ] = {0,1,2,3,1,2,3,2,3,3};
    const float* rp = rpart + (size_t)cls * (NQ * 256);
#pragma unroll
    for (int q = 0; q < NQ; ++q) {
        f32x4 s = (f32x4){0.f, 0.f, 0.f, 0.f};
#pragma unroll
        for (int ch = 0; ch < CH; ++ch)
            s += *reinterpret_cast<const f32x4*>(rp + (size_t)ch * (NCLS * NQ * 256) + q * 256 + (i << 2));
        const int row0 = QMB[q] * 16 + ((i >> 4) << 2);
        const int colo = QNB[q] * 16 + (i & 15);
#pragma unroll
        for (int rr = 0; rr < 4; ++rr) {
            M[row0 + rr][colo] = s[rr];
            M[colo][row0 + rr] = s[rr];
        }
    }
    __syncthreads();

    float row[64];
#pragma unroll
    for (int c2 = 0; c2 < 64; ++c2)
        row[c2] = M[i][c2] * inv + (c2 == i ? 1.0f : 0.0f);

#pragma unroll
    for (int j = 0; j < 64; ++j) {
        const float piv = __shfl(row[j], j);
        const float li  = row[j] * rsqrtf(piv);
        lcol[i] = li;
        __syncthreads();
#pragma unroll
        for (int c2 = j + 1; c2 < 64; ++c2)
            row[c2] -= li * lcol[c2];
        __syncthreads();
    }

    float slog = 0.f;
#pragma unroll
    for (int j = 0; j < 64; ++j)
        if (i == j) slog = __logf(row[j]);
    slog += __shfl_down(slog, 32); slog += __shfl_down(slog, 16);
    slog += __shfl_down(slog, 8);  slog += __shfl_down(slog, 4);
    slog += __shfl_down(slog, 2);  slog += __shfl_down(slog, 1);
    if (i == 0) atomicAdd(out, 0.5f * slog);
}

// ---------- launcher ----------
extern "C" void kernel_launch(void* const* d_in, const int* in_sizes, int n_in,
                              void* d_out, int out_size, void* d_ws, size_t ws_size,
                              hipStream_t stream) {
    const float* h    = (const float*)d_in[0];
    const int*   yhat = (const int*)d_in[1];
    const int    N    = in_sizes[1];
    float* out = (float*)d_out;

    // ws layout: [rpart CH*100*256 f32][cntp G*16 int][partials G*PPB f16]
    const size_t rpart_sz = (size_t)CH * NCLS * NQ * 256 * sizeof(float);
    const size_t cntp_off = rpart_sz;

    const int ntiles = (N + TILE - 1) / TILE;
    int G = 512;    // 2 blocks per CU
    {
        const size_t perG = 64 + (size_t)PPB * sizeof(_Float16);
        if (ws_size > rpart_sz) {
            size_t maxG = (ws_size - rpart_sz) / perG;
            if ((size_t)G > maxG) G = (int)maxG;
        } else G = 1;
        if (G < 1) G = 1;
    }
    if (G > ntiles) G = ntiles;

    const size_t partials_off = cntp_off + (size_t)G * 16 * sizeof(int);
    float*    rpart    = (float*)d_ws;
    int*      cntp     = (int*)((char*)d_ws + cntp_off);
    _Float16* partials = (_Float16*)((char*)d_ws + partials_off);

    HL_gram<<<G, TPB, 0, stream>>>(h, yhat, partials, cntp, N, ntiles, G);

    int CS = (G + CH - 1) / CH;
    const int rthreads = CH * NCLS * NQ * 64;
    HL_reduce<<<(rthreads + 255) / 256, 256, 0, stream>>>(partials, rpart, out, G, CS);

    HL_chol<<<NCLS, 64, 0, stream>>>(rpart, cntp, out, G);
}

// Round 14
// 83.633 us; speedup vs baseline: 3.4202x; 1.6746x over previous
//
#include <hip/hip_runtime.h>
#include <hip/hip_bf16.h>

// ---------- types ----------
typedef __attribute__((ext_vector_type(8))) short    short8;
typedef __attribute__((ext_vector_type(4))) float    f32x4;
typedef __attribute__((ext_vector_type(4))) _Float16 f16x4;
typedef __attribute__((ext_vector_type(2))) unsigned u32x2;
typedef __attribute__((ext_vector_type(4))) unsigned u32x4;
typedef __attribute__((ext_vector_type(4))) int      i32x4;

#define NCLS 10
#define TILE 128           // rows per tile (4 k-slices of 32)
#define TPB  1024          // 16 waves; 1 block/CU (100 KB LDS)
#define NQ   10            // upper-triangular 16x16 quads of 64x64 Gram
#define PPB  (NCLS * NQ * 256)   // halves per block of partials
#define CH   16            // reduction chunks

#define AS1 __attribute__((address_space(1)))
#define AS3 __attribute__((address_space(3)))

#define MF(a, b, c) __builtin_amdgcn_mfma_f32_16x16x32_bf16((a), (b), (c), 0, 0, 0)

static __device__ __forceinline__ unsigned pkbf2(float a, float b) {
    __hip_bfloat162 p = __float22bfloat162_rn(make_float2(a, b));
    unsigned u; __builtin_memcpy(&u, &p, 4);
    return u;
}
static __device__ __forceinline__ unsigned pkh2(float a, float b) {
    unsigned short ha = __builtin_bit_cast(unsigned short, (_Float16)a);
    unsigned short hb = __builtin_bit_cast(unsigned short, (_Float16)b);
    return (unsigned)ha | ((unsigned)hb << 16);
}
static __device__ __forceinline__ unsigned umin2(unsigned a, unsigned b) {
    return a < b ? a : b;
}

// ---------- compute one tile: one full class per wave; in-register masks ----------
// hs layout: byte(d,row) = d*256 + (row>>6)*128 + ((((row>>3)&7)*16) ^ ((d&7)<<4))
//            + (row&7)*2   — write & read both verified 8-cyc/instr optimal.
static __device__ __forceinline__ void compute_tile(
        const char* hsb, const char* yb, int vr, int cls, int hi, int col,
        f32x4 (&acc)[NQ], int& cnt) {
    const int xbase = col * 256 + ((hi << 4) ^ ((col & 7) << 4));
    const bool guard = (vr < TILE);
#pragma unroll
    for (int ks = 0; ks < 4; ++ks) {
        const int ro = (xbase ^ ((ks & 1) << 6)) + (ks >> 1) * 128;
        // y values for this lane's 8 k-rows (broadcast reads, conflict-free)
        i32x4 ya = *(const i32x4*)(yb + ks * 128 + hi * 32);
        i32x4 yc = *(const i32x4*)(yb + ks * 128 + hi * 32 + 16);
        if (guard) {
            const int krow = ks * 32 + hi * 8;
            ya[0] = (krow + 0 < vr) ? ya[0] : -1;
            ya[1] = (krow + 1 < vr) ? ya[1] : -1;
            ya[2] = (krow + 2 < vr) ? ya[2] : -1;
            ya[3] = (krow + 3 < vr) ? ya[3] : -1;
            yc[0] = (krow + 4 < vr) ? yc[0] : -1;
            yc[1] = (krow + 5 < vr) ? yc[1] : -1;
            yc[2] = (krow + 6 < vr) ? yc[2] : -1;
            yc[3] = (krow + 7 < vr) ? yc[3] : -1;
        }
        short8 m;
        m[0] = (ya[0] == cls) ? (short)-1 : (short)0;
        m[1] = (ya[1] == cls) ? (short)-1 : (short)0;
        m[2] = (ya[2] == cls) ? (short)-1 : (short)0;
        m[3] = (ya[3] == cls) ? (short)-1 : (short)0;
        m[4] = (yc[0] == cls) ? (short)-1 : (short)0;
        m[5] = (yc[1] == cls) ? (short)-1 : (short)0;
        m[6] = (yc[2] == cls) ? (short)-1 : (short)0;
        m[7] = (yc[3] == cls) ? (short)-1 : (short)0;
        cnt += (ya[0] == cls) + (ya[1] == cls) + (ya[2] == cls) + (ya[3] == cls)
             + (yc[0] == cls) + (yc[1] == cls) + (yc[2] == cls) + (yc[3] == cls);

        short8 am[4];
#pragma unroll
        for (int nb = 0; nb < 4; ++nb)
            am[nb] = *(const short8*)(hsb + ro + nb * 4096) & m;
        __builtin_amdgcn_s_setprio(1);
        acc[0] = MF(am[0], am[0], acc[0]);
        acc[1] = MF(am[0], am[1], acc[1]);
        acc[2] = MF(am[0], am[2], acc[2]);
        acc[3] = MF(am[0], am[3], acc[3]);
        acc[4] = MF(am[1], am[1], acc[4]);
        acc[5] = MF(am[1], am[2], acc[5]);
        acc[6] = MF(am[1], am[3], acc[6]);
        acc[7] = MF(am[2], am[2], acc[7]);
        acc[8] = MF(am[2], am[3], acc[8]);
        acc[9] = MF(am[3], am[3], acc[9]);
        __builtin_amdgcn_s_setprio(0);
    }
}

// ---------- kernel 1: masked Grams; TILE=128, 16 waves, 1 barrier/tile ----------
// partials: [G][NCLS][NQ][256] f16; cntp: [G][16] int. Both fully overwritten.
__global__ __launch_bounds__(TPB, 4) void HL_gram(
        const float* __restrict__ h, const int* __restrict__ yhat,
        _Float16* __restrict__ partials, int* __restrict__ cntp,
        int N, int ntiles, int G) {
    __shared__ __align__(16) float          fs[2][TILE * 64];    // 64 KB fp32
    __shared__ __align__(16) unsigned short hs[2][64 * TILE];    // 32 KB bf16 swz
    __shared__ __align__(16) int            ylds[4][TILE];       // 2 KB, 4-ring

    const int tid  = threadIdx.x;
    const int wid  = tid >> 6;      // 0..15
    const int lane = tid & 63;
    const int hi   = lane >> 4;
    const int col  = lane & 15;
    const int cls  = wid;           // waves 0..9 compute class wid

    f32x4 acc[NQ];
#pragma unroll
    for (int q = 0; q < NQ; ++q) acc[q] = (f32x4){0.f, 0.f, 0.f, 0.f};
    int cnt = 0;

    const int bid = blockIdx.x;
    const int K   = (ntiles - bid + G - 1) / G;

    // ---- 32-bit additive DMA source offsets (bytes) ----
    const unsigned step  = (unsigned)G * (TILE * 256u);
    const unsigned maxh  = (unsigned)(N - 4) * 256u + (unsigned)lane * 16u;
    unsigned offh = (unsigned)bid * (TILE * 256u) + (unsigned)wid * 2048u
                  + (unsigned)lane * 16u;
    const unsigned ystep = (unsigned)G * (TILE * 4u);
    const unsigned maxy  = (unsigned)(N - 4) * 4u;
    unsigned offy = (unsigned)bid * (TILE * 4u) + (unsigned)lane * 16u;

    char* fdst0 = (char*)&fs[0][0] + wid * 2048;   // wave-uniform LDS dests
    char* fdst1 = (char*)&fs[1][0] + wid * 2048;

    // ---- prologue: DMA tile 0 -> fs[0], ylds[0] ----
    {
        const unsigned o0 = umin2(offh, maxh);
        const unsigned o1 = umin2(offh + 1024u, maxh);
        __builtin_amdgcn_global_load_lds((const AS1 float*)((const char*)h + o0),
                                         (AS3 float*)fdst0, 16, 0, 0);
        __builtin_amdgcn_global_load_lds((const AS1 float*)((const char*)h + o1),
                                         (AS3 float*)(fdst0 + 1024), 16, 0, 0);
        if (wid == 15 && lane < 32) {
            const unsigned oy = umin2(offy, maxy);
            __builtin_amdgcn_global_load_lds((const AS1 int*)((const char*)yhat + oy),
                                             (AS3 int*)&ylds[0][0], 16, 0, 0);
        }
        offh += step; offy += ystep;
    }

    for (int k = 0; k < K; ++k) {
        const int slot = k & 1;

        // ---- entry: DMA(k) drained; phase-(k-1) LDS writes visible ----
        asm volatile("s_waitcnt vmcnt(0)" ::: "memory");
        asm volatile("s_waitcnt lgkmcnt(0)" ::: "memory");
        __builtin_amdgcn_s_barrier();
        __builtin_amdgcn_sched_barrier(0);

        // ---- issue DMA(k+1): fs[slot^1], ylds[(k+1)&3] ----
        if (k + 1 < K) {
            char* fd = slot ? fdst0 : fdst1;
            const unsigned o0 = umin2(offh, maxh);
            const unsigned o1 = umin2(offh + 1024u, maxh);
            __builtin_amdgcn_global_load_lds((const AS1 float*)((const char*)h + o0),
                                             (AS3 float*)fd, 16, 0, 0);
            __builtin_amdgcn_global_load_lds((const AS1 float*)((const char*)h + o1),
                                             (AS3 float*)(fd + 1024), 16, 0, 0);
            if (wid == 15 && lane < 32) {
                const unsigned oy = umin2(offy, maxy);
                __builtin_amdgcn_global_load_lds((const AS1 int*)((const char*)yhat + oy),
                                                 (AS3 int*)&ylds[(k + 1) & 3][0], 16, 0, 0);
            }
            offh += step; offy += ystep;
        }

        // ---- convert tile k: wave w owns rows w*8..+7, lane = d ----
        {
            const float* fp = &fs[slot][0] + wid * 512 + lane;
            const float x0 = fp[0],   x1 = fp[64],  x2 = fp[128], x3 = fp[192];
            const float x4 = fp[256], x5 = fp[320], x6 = fp[384], x7 = fp[448];
            u32x4 v;
            v[0] = pkbf2(x0, x1); v[1] = pkbf2(x2, x3);
            v[2] = pkbf2(x4, x5); v[3] = pkbf2(x6, x7);
            char* hb = (char*)&hs[slot][0] + lane * 256 + (wid >> 3) * 128
                     + (((wid & 7) * 16) ^ ((lane & 7) << 4));
            *(u32x4*)hb = v;
        }

        // ---- compute tile k-1 (hs[slot^1], ylds[(k-1)&3]) ----
        if (k > 0 && wid < NCLS) {
            const int vr = N - (bid + (k - 1) * G) * TILE;
            compute_tile((const char*)&hs[slot ^ 1][0],
                         (const char*)&ylds[(k - 1) & 3][0],
                         vr, cls, hi, col, acc, cnt);
        }
    }

    // ---- epilogue: compute the last converted tile ----
    asm volatile("s_waitcnt lgkmcnt(0)" ::: "memory");
    __builtin_amdgcn_s_barrier();
    __builtin_amdgcn_sched_barrier(0);
    if (wid < NCLS) {
        const int vr = N - (bid + (K - 1) * G) * TILE;
        compute_tile((const char*)&hs[(K - 1) & 1][0],
                     (const char*)&ylds[(K - 1) & 3][0],
                     vr, cls, hi, col, acc, cnt);

        // counts: lanes within a hi-group counted the same rows; sum hi groups
        cnt += __shfl_xor(cnt, 16);
        cnt += __shfl_xor(cnt, 32);

        // stream partials (f16)
        _Float16* po = partials + (size_t)bid * PPB + (size_t)cls * (NQ * 256);
#pragma unroll
        for (int q = 0; q < NQ; ++q) {
            u32x2 pk;
            pk[0] = pkh2(acc[q][0], acc[q][1]);
            pk[1] = pkh2(acc[q][2], acc[q][3]);
            *(u32x2*)(po + q * 256 + (lane << 2)) = pk;
        }
        if (lane == 0) cntp[bid * 16 + cls] = cnt;
    }
}

// ---------- kernel 2: chunked block-reduction of f16 partials (atomic-free) ----------
__global__ void HL_reduce(const _Float16* __restrict__ partials, float* __restrict__ rpart,
                          float* __restrict__ out, int G, int CS) {
    const int idx = blockIdx.x * blockDim.x + threadIdx.x;
    if (blockIdx.x == 0 && threadIdx.x == 0) out[0] = 0.f;
    if (idx >= CH * NCLS * NQ * 64) return;
    const int ch = idx / (NCLS * NQ * 64);
    const int r  = idx % (NCLS * NQ * 64);
    const int cq = r >> 6;
    const int l  = r & 63;

    int b0 = ch * CS;
    int b1 = b0 + CS; if (b1 > G) b1 = G;

    f32x4 s = (f32x4){0.f, 0.f, 0.f, 0.f};
    const _Float16* p = partials + (size_t)cq * 256 + (l << 2);
    for (int b = b0; b < b1; ++b) {
        f16x4 v = *(const f16x4*)(p + (size_t)b * PPB);
        s[0] += (float)v[0]; s[1] += (float)v[1];
        s[2] += (float)v[2]; s[3] += (float)v[3];
    }
    *reinterpret_cast<f32x4*>(rpart + ((size_t)ch * (NCLS * NQ) + cq) * 256 + (l << 2)) = s;
}

// ---------- kernel 3: counts + M = 0.5*G/cnt + I; loss += 0.5*logdet ----------
__global__ __launch_bounds__(64, 1) void HL_chol(
        const float* __restrict__ rpart, const int* __restrict__ cntp,
        float* __restrict__ out, int G) {
    __shared__ float M[64][68];
    __shared__ float lcol[64];
    const int cls = blockIdx.x;
    const int i   = threadIdx.x;   // lane 0..63

    int c = 0;
    for (int b = i; b < G; b += 64) c += cntp[b * 16 + cls];
#pragma unroll
    for (int off = 32; off > 0; off >>= 1) c += __shfl_xor(c, off);
    const float inv = 0.5f / (float)c;

    const int QMB[NQ] = {0,0,0,0,1,1,1,2,2,3};
    const int QNB[NQ] = {0,1,2,3,1,2,3,2,3,3};
    const float* rp = rpart + (size_t)cls * (NQ * 256);
#pragma unroll
    for (int q = 0; q < NQ; ++q) {
        f32x4 s = (f32x4){0.f, 0.f, 0.f, 0.f};
#pragma unroll
        for (int ch = 0; ch < CH; ++ch)
            s += *reinterpret_cast<const f32x4*>(rp + (size_t)ch * (NCLS * NQ * 256) + q * 256 + (i << 2));
        const int row0 = QMB[q] * 16 + ((i >> 4) << 2);
        const int colo = QNB[q] * 16 + (i & 15);
#pragma unroll
        for (int rr = 0; rr < 4; ++rr) {
            M[row0 + rr][colo] = s[rr];
            M[colo][row0 + rr] = s[rr];
        }
    }
    __syncthreads();

    float row[64];
#pragma unroll
    for (int c2 = 0; c2 < 64; ++c2)
        row[c2] = M[i][c2] * inv + (c2 == i ? 1.0f : 0.0f);

#pragma unroll
    for (int j = 0; j < 64; ++j) {
        const float piv = __shfl(row[j], j);
        const float li  = row[j] * rsqrtf(piv);
        lcol[i] = li;
        __syncthreads();
#pragma unroll
        for (int c2 = j + 1; c2 < 64; ++c2)
            row[c2] -= li * lcol[c2];
        __syncthreads();
    }

    float slog = 0.f;
#pragma unroll
    for (int j = 0; j < 64; ++j)
        if (i == j) slog = __logf(row[j]);
    slog += __shfl_down(slog, 32); slog += __shfl_down(slog, 16);
    slog += __shfl_down(slog, 8);  slog += __shfl_down(slog, 4);
    slog += __shfl_down(slog, 2);  slog += __shfl_down(slog, 1);
    if (i == 0) atomicAdd(out, 0.5f * slog);
}

// ---------- launcher ----------
extern "C" void kernel_launch(void* const* d_in, const int* in_sizes, int n_in,
                              void* d_out, int out_size, void* d_ws, size_t ws_size,
                              hipStream_t stream) {
    const float* h    = (const float*)d_in[0];
    const int*   yhat = (const int*)d_in[1];
    const int    N    = in_sizes[1];
    float* out = (float*)d_out;

    // ws layout: [rpart CH*100*256 f32][cntp G*16 int][partials G*PPB f16]
    const size_t rpart_sz = (size_t)CH * NCLS * NQ * 256 * sizeof(float);
    const size_t cntp_off = rpart_sz;

    const int ntiles = (N + TILE - 1) / TILE;
    int G = 256;    // 1 block per CU (100 KB LDS)
    {
        const size_t perG = 64 + (size_t)PPB * sizeof(_Float16);
        if (ws_size > rpart_sz) {
            size_t maxG = (ws_size - rpart_sz) / perG;
            if ((size_t)G > maxG) G = (int)maxG;
        } else G = 1;
        if (G < 1) G = 1;
    }
    if (G > ntiles) G = ntiles;

    const size_t partials_off = cntp_off + (size_t)G * 16 * sizeof(int);
    float*    rpart    = (float*)d_ws;
    int*      cntp     = (int*)((char*)d_ws + cntp_off);
    _Float16* partials = (_Float16*)((char*)d_ws + partials_off);

    HL_gram<<<G, TPB, 0, stream>>>(h, yhat, partials, cntp, N, ntiles, G);

    int CS = (G + CH - 1) / CH;
    const int rthreads = CH * NCLS * NQ * 64;
    HL_reduce<<<(rthreads + 255) / 256, 256, 0, stream>>>(partials, rpart, out, G, CS);

    HL_chol<<<NCLS, 64, 0, stream>>>(rpart, cntp, out, G);
}